// Round 13
// baseline (1214.574 us; speedup 1.0000x reference)
//
#include <hip/hip_runtime.h>

#define HID 128
#define NH 8
#define DH 16
#define NLAYERS 7
#define MLP_IN 285
#define MP 288
#define LDW 296         // LDS row stride bf16 elems (edge kernel); 592 B = 37 granules (odd)
#define XS 136          // LDS row stride for node bf16 tiles

typedef short short8 __attribute__((ext_vector_type(8)));
typedef float f32x4 __attribute__((ext_vector_type(4)));
typedef float f32x16 __attribute__((ext_vector_type(16)));
typedef unsigned short ushort8 __attribute__((ext_vector_type(8)));

__device__ inline unsigned short f2bf(float f) {
    union { float f; unsigned int u; } v; v.f = f;
    unsigned int r = v.u + 0x7FFF + ((v.u >> 16) & 1);
    return (unsigned short)(r >> 16);
}
__device__ inline float bf2f(unsigned short u) {
    union { unsigned int u; float f; } v; v.u = ((unsigned int)u) << 16;
    return v.f;
}

// ---------------- embed ----------------
__global__ __launch_bounds__(256) void embed_kernel(
    const float* __restrict__ nf, const float* __restrict__ We,
    const float* __restrict__ be, float* __restrict__ h, int N)
{
    int idx = blockIdx.x * 256 + threadIdx.x;
    if (idx >= N * HID) return;
    int n = idx >> 7, j = idx & 127;
    h[idx] = fmaf(nf[n * 2], We[j], fmaf(nf[n * 2 + 1], We[HID + j], be[j]));
}

// ---------------- prep: node weights -> fragment-major bf16 hi/lo ----------------
__global__ __launch_bounds__(256) void prep_nodew_kernel(
    const float* __restrict__ WQ, const float* __restrict__ WK,
    const float* __restrict__ WV, const float* __restrict__ WO,
    const float* __restrict__ W1, const float* __restrict__ W2,
    unsigned short* __restrict__ wnh, unsigned short* __restrict__ wnl)
{
    int idx = blockIdx.x * 256 + threadIdx.x;
    if (idx >= 42 * 32 * 64) return;
    int lane = idx & 63;
    int r = idx >> 6;
    int kt = r & 7; r >>= 3;
    int ct = r & 3; r >>= 2;
    int m = r;
    int l = m / 6, wi = m - l * 6;
    const float* Wb;
    switch (wi) {
        case 0: Wb = WQ; break; case 1: Wb = WK; break; case 2: Wb = WV; break;
        case 3: Wb = WO; break; case 4: Wb = W1; break; default: Wb = W2; break;
    }
    Wb += (size_t)l * HID * HID;
    int n = ct * 32 + (lane & 31);
    int kb = kt * 16 + (lane >> 5) * 8;
    ushort8 vh, vl;
#pragma unroll
    for (int j = 0; j < 8; ++j) {
        float w = Wb[(size_t)(kb + j) * HID + n];
        unsigned short hi = f2bf(w);
        vh[j] = hi;
        vl[j] = f2bf(w - bf2f(hi));
    }
    *(ushort8*)&wnh[(size_t)idx * 8] = vh;
    *(ushort8*)&wnl[(size_t)idx * 8] = vl;
}

#define LOADB(m, BH, BL) do { \
    size_t fb_ = (((size_t)(matbase + (m)) * 32 + (size_t)wave * 8) * 64 + lane) * 8; \
    const unsigned short* Bh_ = wnh + fb_; \
    const unsigned short* Bl_ = wnl + fb_; \
    _Pragma("unroll") \
    for (int kt = 0; kt < 8; ++kt) { \
        BH[kt] = *(const short8*)&Bh_[kt * 512]; \
        BL[kt] = *(const short8*)&Bl_[kt * 512]; \
    } \
    __builtin_amdgcn_sched_barrier(0); \
} while (0)

#define COMPSTORE(BH, BL, BIAS, OUT, STRIDE, OFF) do { \
    f32x16 acc = {}; \
    _Pragma("unroll") \
    for (int kt = 0; kt < 8; ++kt) \
        acc = __builtin_amdgcn_mfma_f32_32x32x16_bf16(ah[kt], BH[kt], acc, 0, 0, 0); \
    _Pragma("unroll") \
    for (int kt = 0; kt < 8; ++kt) \
        acc = __builtin_amdgcn_mfma_f32_32x32x16_bf16(al[kt], BH[kt], acc, 0, 0, 0); \
    _Pragma("unroll") \
    for (int kt = 0; kt < 8; ++kt) \
        acc = __builtin_amdgcn_mfma_f32_32x32x16_bf16(ah[kt], BL[kt], acc, 0, 0, 0); \
    int col_ = wave * 32 + l31; \
    float bv_ = (BIAS)[col_]; \
    _Pragma("unroll") \
    for (int r = 0; r < 16; ++r) { \
        int rowm_ = (r & 3) + 8 * (r >> 2) + 4 * half; \
        int row_ = rowBase + rowm_; \
        if (row_ < M) (OUT)[(size_t)row_ * (STRIDE) + (OFF) + col_] = acc[r] + bv_; \
    } \
} while (0)

// Row-parallel LayerNorm from f32 LDS SRC[32][132] -> bf16 hi/lo DST.
#define PAR_LN(SRC, GAMMA, BETA, DH_, DL_) do { \
    int r_ = tid >> 3, sg_ = tid & 7; \
    float x_[16]; \
    _Pragma("unroll") \
    for (int j = 0; j < 4; ++j) \
        *(float4*)&x_[j * 4] = *(const float4*)&SRC[r_][sg_ * 16 + j * 4]; \
    float s_ = 0.f; \
    _Pragma("unroll") \
    for (int j = 0; j < 16; ++j) s_ += x_[j]; \
    s_ += __shfl_xor(s_, 1, 64); \
    s_ += __shfl_xor(s_, 2, 64); \
    s_ += __shfl_xor(s_, 4, 64); \
    float mu_ = s_ * (1.0f / 128.0f); \
    float v_ = 0.f; \
    _Pragma("unroll") \
    for (int j = 0; j < 16; ++j) { float d_ = x_[j] - mu_; v_ = fmaf(d_, d_, v_); } \
    v_ += __shfl_xor(v_, 1, 64); \
    v_ += __shfl_xor(v_, 2, 64); \
    v_ += __shfl_xor(v_, 4, 64); \
    float rr_ = rsqrtf(v_ * (1.0f / 128.0f) + 1e-5f); \
    _Pragma("unroll") \
    for (int j = 0; j < 16; ++j) { \
        int c_ = sg_ * 16 + j; \
        float xv_ = (x_[j] - mu_) * rr_ * (GAMMA)[c_] + (BETA)[c_]; \
        unsigned short hi_ = f2bf(xv_); \
        DH_[r_][c_] = hi_; \
        DL_[r_][c_] = f2bf(xv_ - bf2f(hi_)); \
    } \
} while (0)

// ---------------- fused LN1 + QKV (r10: (256,3) co-resident) ----------------
__global__ __launch_bounds__(256, 3) void ln_qkv_mfma(
    const float* __restrict__ h,
    const float* __restrict__ g, const float* __restrict__ bb,
    const unsigned short* __restrict__ wnh, const unsigned short* __restrict__ wnl,
    int matbase,
    const float* __restrict__ bQ, const float* __restrict__ bK, const float* __restrict__ bV,
    float* __restrict__ qo, float* __restrict__ kvo, int M)
{
    __shared__ unsigned short Xh[32][XS];
    __shared__ unsigned short Xl[32][XS];
    __shared__ float Hs[32][132];
    int tid = threadIdx.x;
    int lane = tid & 63, wave = tid >> 6;
    int rowBase = blockIdx.x * 32;

    for (int i = tid; i < 32 * 32; i += 256) {
        int r = i >> 5, c4 = i & 31;
        int row = rowBase + r;
        float4 vh = make_float4(0.f, 0.f, 0.f, 0.f);
        if (row < M) vh = *(const float4*)&h[(size_t)row * HID + c4 * 4];
        *(float4*)&Hs[r][c4 * 4] = vh;
    }
    __syncthreads();

    PAR_LN(Hs, g, bb, Xh, Xl);
    __syncthreads();

    int l31 = lane & 31;
    int half = lane >> 5;

    short8 ah[8], al[8];
#pragma unroll
    for (int kt = 0; kt < 8; ++kt) {
        ah[kt] = *(const short8*)&Xh[l31][kt * 16 + half * 8];
        al[kt] = *(const short8*)&Xl[l31][kt * 16 + half * 8];
    }

    short8 bh0[8], bl0[8];
    LOADB(0, bh0, bl0);
    COMPSTORE(bh0, bl0, bQ, qo, HID, 0);
    LOADB(1, bh0, bl0);
    COMPSTORE(bh0, bl0, bK, kvo, 256, 0);
    LOADB(2, bh0, bl0);
    COMPSTORE(bh0, bl0, bV, kvo, 256, 128);
}

// ---------------- fused WO+res -> LN2 -> W1+relu -> W2+res -> LN1' -> QKV' ----------------
__global__ __launch_bounds__(256, 3) void post_qkv_mfma(
    const float* __restrict__ at, const float* __restrict__ hin,
    const unsigned short* __restrict__ wnh, const unsigned short* __restrict__ wnl,
    int matbase,                      // l*6; WO=+3, W1=+4, W2=+5, next QKV=+6,+7,+8
    const float* __restrict__ bO,
    const float* __restrict__ g2, const float* __restrict__ b2g,
    const float* __restrict__ b1, const float* __restrict__ b2,
    float* __restrict__ hout,
    int doQkv,
    const float* __restrict__ g1n, const float* __restrict__ b1n,
    const float* __restrict__ bQn, const float* __restrict__ bKn, const float* __restrict__ bVn,
    float* __restrict__ qout, float* __restrict__ kvout,
    unsigned short* __restrict__ hbout,   // bf16 h, written on last layer
    int M)
{
    __shared__ unsigned short Ah[32][XS];
    __shared__ unsigned short Al[32][XS];
    __shared__ unsigned short Th[32][XS];
    __shared__ unsigned short Tl[32][XS];
    __shared__ float Hs[32][132];
    int tid = threadIdx.x;
    int lane = tid & 63, wave = tid >> 6;
    int rowBase = blockIdx.x * 32;
    int l31 = lane & 31;
    int half = lane >> 5;

    for (int i = tid; i < 32 * 32; i += 256) {
        int r = i >> 5, c4 = i & 31;
        int row = rowBase + r;
        float4 va = make_float4(0.f, 0.f, 0.f, 0.f), vh = va;
        if (row < M) {
            va = *(const float4*)&at[(size_t)row * HID + c4 * 4];
            vh = *(const float4*)&hin[(size_t)row * HID + c4 * 4];
        }
        const float* vp = (const float*)&va;
#pragma unroll
        for (int q = 0; q < 4; ++q) {
            unsigned short hi = f2bf(vp[q]);
            Ah[r][c4 * 4 + q] = hi;
            Al[r][c4 * 4 + q] = f2bf(vp[q] - bf2f(hi));
        }
        *(float4*)&Hs[r][c4 * 4] = vh;
    }
    __syncthreads();

    int colW = wave * 32 + l31;

    // GEMM1: Hs += at @ WO + bO
    {
        short8 ah[8], al[8];
#pragma unroll
        for (int kt = 0; kt < 8; ++kt) {
            ah[kt] = *(const short8*)&Ah[l31][kt * 16 + half * 8];
            al[kt] = *(const short8*)&Al[l31][kt * 16 + half * 8];
        }
        short8 bh[8], bl[8];
        {
            size_t fb = (((size_t)(matbase + 3) * 32 + (size_t)wave * 8) * 64 + lane) * 8;
            const unsigned short* Bh = wnh + fb;
            const unsigned short* Bl = wnl + fb;
#pragma unroll
            for (int kt = 0; kt < 8; ++kt) {
                bh[kt] = *(const short8*)&Bh[kt * 512];
                bl[kt] = *(const short8*)&Bl[kt * 512];
            }
            __builtin_amdgcn_sched_barrier(0);
        }
        f32x16 acc = {};
#pragma unroll
        for (int kt = 0; kt < 8; ++kt)
            acc = __builtin_amdgcn_mfma_f32_32x32x16_bf16(ah[kt], bh[kt], acc, 0, 0, 0);
#pragma unroll
        for (int kt = 0; kt < 8; ++kt)
            acc = __builtin_amdgcn_mfma_f32_32x32x16_bf16(al[kt], bh[kt], acc, 0, 0, 0);
#pragma unroll
        for (int kt = 0; kt < 8; ++kt)
            acc = __builtin_amdgcn_mfma_f32_32x32x16_bf16(ah[kt], bl[kt], acc, 0, 0, 0);
        float bv = bO[colW];
#pragma unroll
        for (int r = 0; r < 16; ++r) {
            int rowm = (r & 3) + 8 * (r >> 2) + 4 * half;
            Hs[rowm][colW] += acc[r] + bv;
        }
    }
    __syncthreads();

    // LN2 (row-parallel)
    PAR_LN(Hs, g2, b2g, Ah, Al);
    __syncthreads();

    // GEMM2: T = relu(x @ W1 + b1)
    {
        short8 ah[8], al[8];
#pragma unroll
        for (int kt = 0; kt < 8; ++kt) {
            ah[kt] = *(const short8*)&Ah[l31][kt * 16 + half * 8];
            al[kt] = *(const short8*)&Al[l31][kt * 16 + half * 8];
        }
        short8 bh[8], bl[8];
        {
            size_t fb = (((size_t)(matbase + 4) * 32 + (size_t)wave * 8) * 64 + lane) * 8;
            const unsigned short* Bh = wnh + fb;
            const unsigned short* Bl = wnl + fb;
#pragma unroll
            for (int kt = 0; kt < 8; ++kt) {
                bh[kt] = *(const short8*)&Bh[kt * 512];
                bl[kt] = *(const short8*)&Bl[kt * 512];
            }
            __builtin_amdgcn_sched_barrier(0);
        }
        f32x16 acc = {};
#pragma unroll
        for (int kt = 0; kt < 8; ++kt)
            acc = __builtin_amdgcn_mfma_f32_32x32x16_bf16(ah[kt], bh[kt], acc, 0, 0, 0);
#pragma unroll
        for (int kt = 0; kt < 8; ++kt)
            acc = __builtin_amdgcn_mfma_f32_32x32x16_bf16(al[kt], bh[kt], acc, 0, 0, 0);
#pragma unroll
        for (int kt = 0; kt < 8; ++kt)
            acc = __builtin_amdgcn_mfma_f32_32x32x16_bf16(ah[kt], bl[kt], acc, 0, 0, 0);
        float bv = b1[colW];
#pragma unroll
        for (int r = 0; r < 16; ++r) {
            int rowm = (r & 3) + 8 * (r >> 2) + 4 * half;
            float t = fmaxf(acc[r] + bv, 0.f);
            unsigned short hi = f2bf(t);
            Th[rowm][colW] = hi;
            Tl[rowm][colW] = f2bf(t - bf2f(hi));
        }
    }
    __syncthreads();

    // GEMM3: hn = Hs + T @ W2 + b2
    {
        short8 ah[8], al[8];
#pragma unroll
        for (int kt = 0; kt < 8; ++kt) {
            ah[kt] = *(const short8*)&Th[l31][kt * 16 + half * 8];
            al[kt] = *(const short8*)&Tl[l31][kt * 16 + half * 8];
        }
        short8 bh[8], bl[8];
        {
            size_t fb = (((size_t)(matbase + 5) * 32 + (size_t)wave * 8) * 64 + lane) * 8;
            const unsigned short* Bh = wnh + fb;
            const unsigned short* Bl = wnl + fb;
#pragma unroll
            for (int kt = 0; kt < 8; ++kt) {
                bh[kt] = *(const short8*)&Bh[kt * 512];
                bl[kt] = *(const short8*)&Bl[kt * 512];
            }
            __builtin_amdgcn_sched_barrier(0);
        }
        f32x16 acc = {};
#pragma unroll
        for (int kt = 0; kt < 8; ++kt)
            acc = __builtin_amdgcn_mfma_f32_32x32x16_bf16(ah[kt], bh[kt], acc, 0, 0, 0);
#pragma unroll
        for (int kt = 0; kt < 8; ++kt)
            acc = __builtin_amdgcn_mfma_f32_32x32x16_bf16(al[kt], bh[kt], acc, 0, 0, 0);
#pragma unroll
        for (int kt = 0; kt < 8; ++kt)
            acc = __builtin_amdgcn_mfma_f32_32x32x16_bf16(ah[kt], bl[kt], acc, 0, 0, 0);
        float bv = b2[colW];
#pragma unroll
        for (int r = 0; r < 16; ++r) {
            int rowm = (r & 3) + 8 * (r >> 2) + 4 * half;
            int row = rowBase + rowm;
            float hn = Hs[rowm][colW] + acc[r] + bv;
            Hs[rowm][colW] = hn;
            if (row < M) {
                if (doQkv) hout[(size_t)row * HID + colW] = hn;
                else       hbout[(size_t)row * HID + colW] = f2bf(hn);
            }
        }
    }

    if (!doQkv) return;
    __syncthreads();

    // LN1 (next layer) row-parallel
    PAR_LN(Hs, g1n, b1n, Ah, Al);
    __syncthreads();

    // QKV (next layer) — serial B loads (live set < 170-VGPR cap of (256,3))
    {
        short8 ah[8], al[8];
#pragma unroll
        for (int kt = 0; kt < 8; ++kt) {
            ah[kt] = *(const short8*)&Ah[l31][kt * 16 + half * 8];
            al[kt] = *(const short8*)&Al[l31][kt * 16 + half * 8];
        }
        short8 bh0[8], bl0[8];
        LOADB(6, bh0, bl0);
        COMPSTORE(bh0, bl0, bQn, qout, HID, 0);
        LOADB(7, bh0, bl0);
        COMPSTORE(bh0, bl0, bKn, kvout, 256, 0);
        LOADB(8, bh0, bl0);
        COMPSTORE(bh0, bl0, bVn, kvout, 256, 128);
    }
}

// ---------------- CSR build ----------------
__global__ __launch_bounds__(256) void deg_kernel(
    const int* __restrict__ dst, int* __restrict__ deg, int E)
{
    int e = blockIdx.x * 256 + threadIdx.x;
    if (e < E) atomicAdd(&deg[dst[e]], 1);
}

__global__ __launch_bounds__(256) void scan_kernel(
    const int* __restrict__ deg, int* __restrict__ rowptr,
    int* __restrict__ cursor, int N)
{
    __shared__ int sums[256];
    int tid = threadIdx.x;
    int chunk = (N + 255) / 256;
    int lo = tid * chunk;
    int hi = lo + chunk; if (hi > N) hi = N;
    int s = 0;
    for (int i = lo; i < hi && i >= 0; ++i) s += deg[i];
    sums[tid] = s;
    __syncthreads();
    for (int off = 1; off < 256; off <<= 1) {
        int v = (tid >= off) ? sums[tid - off] : 0;
        __syncthreads();
        sums[tid] += v;
        __syncthreads();
    }
    int base = (tid == 0) ? 0 : sums[tid - 1];
    for (int i = lo; i < hi; ++i) {
        rowptr[i] = base; cursor[i] = base; base += deg[i];
    }
    if (tid == 255) rowptr[N] = sums[255];
}

__global__ __launch_bounds__(256) void scatter_kernel(
    const int* __restrict__ src, const int* __restrict__ dst,
    int* __restrict__ cursor, int* __restrict__ ssrc, int E)
{
    int e = blockIdx.x * 256 + threadIdx.x;
    if (e < E) {
        int p = atomicAdd(&cursor[dst[e]], 1);
        ssrc[p] = src[e];
    }
}

// ---------------- fused segment-softmax attention (r8: 2 waves per node) ----------------
__global__ __launch_bounds__(256) void attn_fused_kernel(
    const float* __restrict__ q, const float* __restrict__ kv,
    const int* __restrict__ rowptr, const int* __restrict__ ssrc,
    float* __restrict__ at, int N)
{
    __shared__ float red[2][2][4][64];   // [nodeSlot][half][acc0,acc1,den0,den1][lane]
    int tid = threadIdx.x;
    int wv = tid >> 6;
    int lane = tid & 63;
    int slot = wv >> 1;
    int hf = wv & 1;
    int node = blockIdx.x * 2 + slot;

    float acc0 = 0.f, acc1 = 0.f, den0 = 0.f, den1 = 0.f;
    if (node < N) {
        int beg = rowptr[node], end = rowptr[node + 1];
        int lenA = (end - beg + 1) >> 1;
        int b = hf ? (beg + lenA) : beg;
        int e = hf ? end : (beg + lenA);
        float q0 = q[(size_t)node * HID + lane];
        float q1 = q[(size_t)node * HID + 64 + lane];
        int i = b;
        for (; i + 2 <= e; i += 2) {
            int s0 = ssrc[i], s1 = ssrc[i + 1];
            const float* kv0 = kv + (size_t)s0 * 256;
            const float* kv1 = kv + (size_t)s1 * 256;
            float k00 = kv0[lane],       k01 = kv0[64 + lane];
            float v00 = kv0[128 + lane], v01 = kv0[192 + lane];
            float k10 = kv1[lane],       k11 = kv1[64 + lane];
            float v10 = kv1[128 + lane], v11 = kv1[192 + lane];
            float p00 = q0 * k00, p01 = q1 * k01;
            float p10 = q0 * k10, p11 = q1 * k11;
#pragma unroll
            for (int off = 1; off < 16; off <<= 1) {
                p00 += __shfl_xor(p00, off, 64);
                p01 += __shfl_xor(p01, off, 64);
                p10 += __shfl_xor(p10, off, 64);
                p11 += __shfl_xor(p11, off, 64);
            }
            float w00 = __expf(p00 * 0.25f), w01 = __expf(p01 * 0.25f);
            float w10 = __expf(p10 * 0.25f), w11 = __expf(p11 * 0.25f);
            den0 += w00 + w10; den1 += w01 + w11;
            acc0 = fmaf(w10, v10, fmaf(w00, v00, acc0));
            acc1 = fmaf(w11, v11, fmaf(w01, v01, acc1));
        }
        if (i < e) {
            int s = ssrc[i];
            const float* kv0 = kv + (size_t)s * 256;
            float k0 = kv0[lane], k1 = kv0[64 + lane];
            float p0 = q0 * k0, p1 = q1 * k1;
#pragma unroll
            for (int off = 1; off < 16; off <<= 1) {
                p0 += __shfl_xor(p0, off, 64);
                p1 += __shfl_xor(p1, off, 64);
            }
            float w0 = __expf(p0 * 0.25f), w1 = __expf(p1 * 0.25f);
            den0 += w0; den1 += w1;
            acc0 = fmaf(w0, kv0[128 + lane], acc0);
            acc1 = fmaf(w1, kv0[192 + lane], acc1);
        }
    }
    red[slot][hf][0][lane] = acc0;
    red[slot][hf][1][lane] = acc1;
    red[slot][hf][2][lane] = den0;
    red[slot][hf][3][lane] = den1;
    __syncthreads();

    if (hf == 0 && node < N) {
        float a0 = red[slot][0][0][lane] + red[slot][1][0][lane];
        float a1 = red[slot][0][1][lane] + red[slot][1][1][lane];
        float d0 = red[slot][0][2][lane] + red[slot][1][2][lane];
        float d1 = red[slot][0][3][lane] + red[slot][1][3][lane];
        at[(size_t)node * HID + lane]      = (d0 > 0.f) ? a0 / d0 : 0.f;
        at[(size_t)node * HID + 64 + lane] = (d1 > 0.f) ? a1 / d1 : 0.f;
    }
}

// ---------------- prep: fragment-major packed bf16 MLP hidden weights ----------------
__global__ __launch_bounds__(256) void prep_wp_kernel(
    const float* __restrict__ Wh, unsigned short* __restrict__ wp)
{
    int idx = blockIdx.x * 256 + threadIdx.x;
    if (idx >= 3 * 9 * 18 * 64) return;
    int lane = idx & 63;
    int r = idx >> 6;
    int kt = r % 18; r /= 18;
    int ct = r % 9;
    int layer = r / 9;
    int n = ct * 32 + (lane & 31);
    int kbase = kt * 16 + (lane >> 5) * 8;
    ushort8 val;
#pragma unroll
    for (int j = 0; j < 8; ++j) {
        int k = kbase + j;
        float v = (n < MLP_IN && k < MLP_IN)
            ? Wh[(size_t)layer * MLP_IN * MLP_IN + (size_t)k * MLP_IN + n] : 0.f;
        val[j] = f2bf(v);
    }
    *(ushort8*)&wp[(size_t)idx * 8] = val;
}

// ---------------- fused edge classifier MLP ----------------
// v13: r12 geometry (32 edges / 4 waves / 18.9KB LDS / (256,4)) + the r5
// sched_barrier(0) load-batch fence. r5 proved the fence adds memory-level
// parallelism per wave (18 loads in flight vs ~1: 410->347us at 8 waves/CU)
// but was only ever run at 2 blocks/CU. Here it runs at r12's ~13 waves/CU.
// Register check: fence forces bfr[18] live (72) + acc(16) + misc ~ 100-115;
// afr rematerializes from LDS (ds_read_b128 ~12cy, pipelined under MFMA) --
// fits the 128-VGPR cap of (256,4) without spill (watch WRITE_SIZE).
__global__ __launch_bounds__(256, 4) void edge_mlp_mfma(
    const unsigned short* __restrict__ hb, const float* __restrict__ ce,
    const float* __restrict__ pe, const float* __restrict__ num,
    const int* __restrict__ src, const int* __restrict__ dst,
    const int* __restrict__ pc, const int* __restrict__ rc,
    const int* __restrict__ pf,
    const unsigned short* __restrict__ wp, const float* __restrict__ bh,
    const float* __restrict__ Wo, const float* __restrict__ bo,
    float* __restrict__ out, int E)
{
    __shared__ unsigned short y[32 * LDW];   // 18,944 B
    int tid = threadIdx.x;
    int e0 = blockIdx.x * 32;
    int wave = tid >> 6;
    int lane = tid & 63;
    int l31 = lane & 31;
    int half = lane >> 5;

    // stage inputs into y (cols 285-287 zeroed via c==35 tail)
    for (int i = tid; i < 32 * 36; i += 256) {
        int t = i / 36;
        int c = i - t * 36;
        int e = e0 + t;
        if (e >= E) e = E - 1;
        ushort8 val;
        if (c < 16) {
            val = *(const ushort8*)&hb[(size_t)src[e] * HID + c * 8];
        } else if (c < 32) {
            val = *(const ushort8*)&hb[(size_t)dst[e] * HID + (c - 16) * 8];
        } else if (c == 32) {
            const float* p = &ce[pc[e] * 8];
#pragma unroll
            for (int j = 0; j < 8; ++j) val[j] = f2bf(p[j]);
        } else if (c == 33) {
            const float* p = &ce[rc[e] * 8];
#pragma unroll
            for (int j = 0; j < 8; ++j) val[j] = f2bf(p[j]);
        } else if (c == 34) {
            const float* p = &pe[pf[e] * 8];
#pragma unroll
            for (int j = 0; j < 8; ++j) val[j] = f2bf(p[j]);
        } else {
            const float* p = &num[(size_t)e * 5];
#pragma unroll
            for (int j = 0; j < 5; ++j) val[j] = f2bf(p[j]);
            val[5] = 0; val[6] = 0; val[7] = 0;
        }
        *(ushort8*)&y[t * LDW + c * 8] = val;
    }
    __syncthreads();

    for (int layer = 0; layer < 3; ++layer) {
        const float* __restrict__ bias = bh + layer * MLP_IN;

        short8 afr[18];
#pragma unroll
        for (int kt = 0; kt < 18; ++kt)
            afr[kt] = *(const short8*)&y[l31 * LDW + kt * 16 + half * 8];
        __syncthreads();   // all reads done before anyone overwrites y

        for (int ct = wave; ct < 9; ct += 4) {
            const unsigned short* __restrict__ Bp =
                wp + (size_t)layer * 82944 + (size_t)ct * 9216 + (size_t)lane * 8;
            short8 bfr[18];
#pragma unroll
            for (int kt = 0; kt < 18; ++kt)
                bfr[kt] = *(const short8*)&Bp[kt * 512];
            __builtin_amdgcn_sched_barrier(0);   // batch all 18 loads ahead of MFMA
            f32x16 acc = {};
#pragma unroll
            for (int kt = 0; kt < 18; ++kt)
                acc = __builtin_amdgcn_mfma_f32_32x32x16_bf16(afr[kt], bfr[kt], acc, 0, 0, 0);
            int col = ct * 32 + l31;
            if (col < MLP_IN) {
                float bv = bias[col];
#pragma unroll
                for (int r = 0; r < 16; ++r) {
                    int rowm = (r & 3) + 8 * (r >> 2) + 4 * half;
                    float t = fmaxf(acc[r] + bv, 0.f);
                    y[rowm * LDW + col] = f2bf(t);
                }
            }
        }
        __syncthreads();   // writes done before next layer's reads
    }

    // final 285x2 projection: 4 threads per edge (oc x K-half), shfl-combine
    {
        int t = tid >> 2;            // 0..63, only t<32 valid
        int oc = tid & 1;
        int kk = (tid >> 1) & 1;
        int e = e0 + t;
        if (t < 32) {
            const unsigned short* yr = &y[t * LDW];
            float p0 = 0.f, p1 = 0.f, p2 = 0.f, p3 = 0.f;
            int kc_lo = kk ? 18 : 0;
            int kc_hi = kk ? 35 : 18;
            for (int kc = kc_lo; kc < kc_hi; ++kc) {
                ushort8 yv = *(const ushort8*)&yr[kc * 8];
                int kb = kc * 8;
                p0 = fmaf(bf2f(yv[0]), Wo[(kb + 0) * 2 + oc], p0);
                p1 = fmaf(bf2f(yv[1]), Wo[(kb + 1) * 2 + oc], p1);
                p2 = fmaf(bf2f(yv[2]), Wo[(kb + 2) * 2 + oc], p2);
                p3 = fmaf(bf2f(yv[3]), Wo[(kb + 3) * 2 + oc], p3);
                p0 = fmaf(bf2f(yv[4]), Wo[(kb + 4) * 2 + oc], p0);
                p1 = fmaf(bf2f(yv[5]), Wo[(kb + 5) * 2 + oc], p1);
                p2 = fmaf(bf2f(yv[6]), Wo[(kb + 6) * 2 + oc], p2);
                p3 = fmaf(bf2f(yv[7]), Wo[(kb + 7) * 2 + oc], p3);
            }
            float acc = (p0 + p1) + (p2 + p3);
            if (kk) {
                for (int k = 280; k < MLP_IN; ++k)
                    acc = fmaf(bf2f(yr[k]), Wo[k * 2 + oc], acc);
            }
            acc += __shfl_xor(acc, 2, 64);
            if (kk == 0 && e < E)
                out[(size_t)e * 2 + oc] = acc + bo[oc];
        }
    }
}

extern "C" void kernel_launch(void* const* d_in, const int* in_sizes, int n_in,
                              void* d_out, int out_size, void* d_ws, size_t ws_size,
                              hipStream_t stream)
{
    const float* node_feats = (const float*)d_in[0];
    const float* numericals = (const float*)d_in[1];
    const float* W_emb = (const float*)d_in[2];
    const float* b_emb = (const float*)d_in[3];
    const float* WQ = (const float*)d_in[4];
    const float* bQ = (const float*)d_in[5];
    const float* WK = (const float*)d_in[6];
    const float* bK = (const float*)d_in[7];
    const float* WV = (const float*)d_in[8];
    const float* bV = (const float*)d_in[9];
    const float* WO = (const float*)d_in[10];
    const float* bO = (const float*)d_in[11];
    const float* ln1_g = (const float*)d_in[12];
    const float* ln1_b = (const float*)d_in[13];
    const float* ln2_g = (const float*)d_in[14];
    const float* ln2_b = (const float*)d_in[15];
    const float* W1 = (const float*)d_in[16];
    const float* b1 = (const float*)d_in[17];
    const float* W2 = (const float*)d_in[18];
    const float* b2 = (const float*)d_in[19];
    const float* curr_emb = (const float*)d_in[20];
    const float* pay_emb = (const float*)d_in[21];
    const float* mlp_Wh = (const float*)d_in[22];
    const float* mlp_bh = (const float*)d_in[23];
    const float* mlp_Wo = (const float*)d_in[24];
    const float* mlp_bo = (const float*)d_in[25];
    const int* src = (const int*)d_in[26];
    const int* dst = (const int*)d_in[27];
    const int* pc = (const int*)d_in[28];
    const int* rc = (const int*)d_in[29];
    const int* pf = (const int*)d_in[30];

    const int N = in_sizes[0] / 2;
    const int E = in_sizes[26];

    float* ws = (float*)d_ws;
    float* h    = ws;
    float* qb0  = h    + (size_t)N * HID;
    float* kvb0 = qb0  + (size_t)N * HID;
    float* qb1  = kvb0 + (size_t)N * HID * 2;
    float* kvb1 = qb1  + (size_t)N * HID;
    float* at   = kvb1 + (size_t)N * HID * 2;
    unsigned short* hb = (unsigned short*)(at + (size_t)N * HID);
    unsigned short* wpk = hb + (size_t)N * HID;
    unsigned short* wnh = wpk + (size_t)3 * 9 * 18 * 64 * 8;
    unsigned short* wnl = wnh + (size_t)42 * 32 * 64 * 8;
    int* rowptr = (int*)(wnl + (size_t)42 * 32 * 64 * 8);
    int* deg    = rowptr + (N + 1);
    int* cursor = deg + N;
    int* ssrc   = cursor + N;

    prep_wp_kernel<<<(3 * 9 * 18 * 64 + 255) / 256, 256, 0, stream>>>(mlp_Wh, wpk);
    prep_nodew_kernel<<<(42 * 32 * 64 + 255) / 256, 256, 0, stream>>>(
        WQ, WK, WV, WO, W1, W2, wnh, wnl);

    embed_kernel<<<(N * HID + 255) / 256, 256, 0, stream>>>(node_feats, W_emb, b_emb, h, N);

    hipMemsetAsync(deg, 0, (size_t)N * sizeof(int), stream);
    deg_kernel<<<(E + 255) / 256, 256, 0, stream>>>(dst, deg, E);
    scan_kernel<<<1, 256, 0, stream>>>(deg, rowptr, cursor, N);
    scatter_kernel<<<(E + 255) / 256, 256, 0, stream>>>(src, dst, cursor, ssrc, E);

    int nodeBlocks = (N + 31) / 32;

    // layer 0 QKV
    ln_qkv_mfma<<<nodeBlocks, 256, 0, stream>>>(
        h, ln1_g, ln1_b, wnh, wnl, 0,
        bQ, bK, bV, qb0, kvb0, N);

    float* qbuf[2]  = { qb0, qb1 };
    float* kvbuf[2] = { kvb0, kvb1 };

    for (int l = 0; l < NLAYERS; ++l) {
        int cur = l & 1, nxt = cur ^ 1;
        int doQkv = (l < NLAYERS - 1) ? 1 : 0;
        int ln = (l + 1 < NLAYERS) ? (l + 1) : 0;

        attn_fused_kernel<<<(N + 1) / 2, 256, 0, stream>>>(
            qbuf[cur], kvbuf[cur], rowptr, ssrc, at, N);

        post_qkv_mfma<<<nodeBlocks, 256, 0, stream>>>(
            at, h, wnh, wnl, l * 6,
            bO + l * HID,
            ln2_g + l * HID, ln2_b + l * HID,
            b1 + l * HID, b2 + l * HID,
            h, doQkv,
            ln1_g + ln * HID, ln1_b + ln * HID,
            bQ + ln * HID, bK + ln * HID, bV + ln * HID,
            qbuf[nxt], kvbuf[nxt],
            hb, N);
    }

    edge_mlp_mfma<<<(E + 31) / 32, 256, 0, stream>>>(
        hb, curr_emb, pay_emb, numericals, src, dst, pc, rc, pf,
        wpk, mlp_bh, mlp_Wo, mlp_bo, (float*)d_out, E);
}

// Round 14
// 899.947 us; speedup vs baseline: 1.3496x; 1.3496x over previous
//
#include <hip/hip_runtime.h>

#define HID 128
#define NH 8
#define DH 16
#define NLAYERS 7
#define MLP_IN 285
#define MP 288
#define LDW 296         // LDS row stride bf16 elems (edge kernel); 592 B = 37 granules (odd)
#define XS 136          // LDS row stride for node bf16 tiles

typedef short short8 __attribute__((ext_vector_type(8)));
typedef float f32x4 __attribute__((ext_vector_type(4)));
typedef float f32x16 __attribute__((ext_vector_type(16)));
typedef unsigned short ushort8 __attribute__((ext_vector_type(8)));

__device__ inline unsigned short f2bf(float f) {
    union { float f; unsigned int u; } v; v.f = f;
    unsigned int r = v.u + 0x7FFF + ((v.u >> 16) & 1);
    return (unsigned short)(r >> 16);
}
__device__ inline float bf2f(unsigned short u) {
    union { unsigned int u; float f; } v; v.u = ((unsigned int)u) << 16;
    return v.f;
}

// ---------------- embed ----------------
__global__ __launch_bounds__(256) void embed_kernel(
    const float* __restrict__ nf, const float* __restrict__ We,
    const float* __restrict__ be, float* __restrict__ h, int N)
{
    int idx = blockIdx.x * 256 + threadIdx.x;
    if (idx >= N * HID) return;
    int n = idx >> 7, j = idx & 127;
    h[idx] = fmaf(nf[n * 2], We[j], fmaf(nf[n * 2 + 1], We[HID + j], be[j]));
}

// ---------------- prep: node weights -> fragment-major bf16 hi/lo ----------------
__global__ __launch_bounds__(256) void prep_nodew_kernel(
    const float* __restrict__ WQ, const float* __restrict__ WK,
    const float* __restrict__ WV, const float* __restrict__ WO,
    const float* __restrict__ W1, const float* __restrict__ W2,
    unsigned short* __restrict__ wnh, unsigned short* __restrict__ wnl)
{
    int idx = blockIdx.x * 256 + threadIdx.x;
    if (idx >= 42 * 32 * 64) return;
    int lane = idx & 63;
    int r = idx >> 6;
    int kt = r & 7; r >>= 3;
    int ct = r & 3; r >>= 2;
    int m = r;
    int l = m / 6, wi = m - l * 6;
    const float* Wb;
    switch (wi) {
        case 0: Wb = WQ; break; case 1: Wb = WK; break; case 2: Wb = WV; break;
        case 3: Wb = WO; break; case 4: Wb = W1; break; default: Wb = W2; break;
    }
    Wb += (size_t)l * HID * HID;
    int n = ct * 32 + (lane & 31);
    int kb = kt * 16 + (lane >> 5) * 8;
    ushort8 vh, vl;
#pragma unroll
    for (int j = 0; j < 8; ++j) {
        float w = Wb[(size_t)(kb + j) * HID + n];
        unsigned short hi = f2bf(w);
        vh[j] = hi;
        vl[j] = f2bf(w - bf2f(hi));
    }
    *(ushort8*)&wnh[(size_t)idx * 8] = vh;
    *(ushort8*)&wnl[(size_t)idx * 8] = vl;
}

#define LOADB(m, BH, BL) do { \
    size_t fb_ = (((size_t)(matbase + (m)) * 32 + (size_t)wave * 8) * 64 + lane) * 8; \
    const unsigned short* Bh_ = wnh + fb_; \
    const unsigned short* Bl_ = wnl + fb_; \
    _Pragma("unroll") \
    for (int kt = 0; kt < 8; ++kt) { \
        BH[kt] = *(const short8*)&Bh_[kt * 512]; \
        BL[kt] = *(const short8*)&Bl_[kt * 512]; \
    } \
    __builtin_amdgcn_sched_barrier(0); \
} while (0)

#define COMPSTORE(BH, BL, BIAS, OUT, STRIDE, OFF) do { \
    f32x16 acc = {}; \
    _Pragma("unroll") \
    for (int kt = 0; kt < 8; ++kt) \
        acc = __builtin_amdgcn_mfma_f32_32x32x16_bf16(ah[kt], BH[kt], acc, 0, 0, 0); \
    _Pragma("unroll") \
    for (int kt = 0; kt < 8; ++kt) \
        acc = __builtin_amdgcn_mfma_f32_32x32x16_bf16(al[kt], BH[kt], acc, 0, 0, 0); \
    _Pragma("unroll") \
    for (int kt = 0; kt < 8; ++kt) \
        acc = __builtin_amdgcn_mfma_f32_32x32x16_bf16(ah[kt], BL[kt], acc, 0, 0, 0); \
    int col_ = wave * 32 + l31; \
    float bv_ = (BIAS)[col_]; \
    _Pragma("unroll") \
    for (int r = 0; r < 16; ++r) { \
        int rowm_ = (r & 3) + 8 * (r >> 2) + 4 * half; \
        int row_ = rowBase + rowm_; \
        if (row_ < M) (OUT)[(size_t)row_ * (STRIDE) + (OFF) + col_] = acc[r] + bv_; \
    } \
} while (0)

// Row-parallel LayerNorm from f32 LDS SRC[32][132] -> bf16 hi/lo DST.
#define PAR_LN(SRC, GAMMA, BETA, DH_, DL_) do { \
    int r_ = tid >> 3, sg_ = tid & 7; \
    float x_[16]; \
    _Pragma("unroll") \
    for (int j = 0; j < 4; ++j) \
        *(float4*)&x_[j * 4] = *(const float4*)&SRC[r_][sg_ * 16 + j * 4]; \
    float s_ = 0.f; \
    _Pragma("unroll") \
    for (int j = 0; j < 16; ++j) s_ += x_[j]; \
    s_ += __shfl_xor(s_, 1, 64); \
    s_ += __shfl_xor(s_, 2, 64); \
    s_ += __shfl_xor(s_, 4, 64); \
    float mu_ = s_ * (1.0f / 128.0f); \
    float v_ = 0.f; \
    _Pragma("unroll") \
    for (int j = 0; j < 16; ++j) { float d_ = x_[j] - mu_; v_ = fmaf(d_, d_, v_); } \
    v_ += __shfl_xor(v_, 1, 64); \
    v_ += __shfl_xor(v_, 2, 64); \
    v_ += __shfl_xor(v_, 4, 64); \
    float rr_ = rsqrtf(v_ * (1.0f / 128.0f) + 1e-5f); \
    _Pragma("unroll") \
    for (int j = 0; j < 16; ++j) { \
        int c_ = sg_ * 16 + j; \
        float xv_ = (x_[j] - mu_) * rr_ * (GAMMA)[c_] + (BETA)[c_]; \
        unsigned short hi_ = f2bf(xv_); \
        DH_[r_][c_] = hi_; \
        DL_[r_][c_] = f2bf(xv_ - bf2f(hi_)); \
    } \
} while (0)

// ---------------- fused LN1 + QKV (r10: (256,3) co-resident) ----------------
__global__ __launch_bounds__(256, 3) void ln_qkv_mfma(
    const float* __restrict__ h,
    const float* __restrict__ g, const float* __restrict__ bb,
    const unsigned short* __restrict__ wnh, const unsigned short* __restrict__ wnl,
    int matbase,
    const float* __restrict__ bQ, const float* __restrict__ bK, const float* __restrict__ bV,
    float* __restrict__ qo, float* __restrict__ kvo, int M)
{
    __shared__ unsigned short Xh[32][XS];
    __shared__ unsigned short Xl[32][XS];
    __shared__ float Hs[32][132];
    int tid = threadIdx.x;
    int lane = tid & 63, wave = tid >> 6;
    int rowBase = blockIdx.x * 32;

    for (int i = tid; i < 32 * 32; i += 256) {
        int r = i >> 5, c4 = i & 31;
        int row = rowBase + r;
        float4 vh = make_float4(0.f, 0.f, 0.f, 0.f);
        if (row < M) vh = *(const float4*)&h[(size_t)row * HID + c4 * 4];
        *(float4*)&Hs[r][c4 * 4] = vh;
    }
    __syncthreads();

    PAR_LN(Hs, g, bb, Xh, Xl);
    __syncthreads();

    int l31 = lane & 31;
    int half = lane >> 5;

    short8 ah[8], al[8];
#pragma unroll
    for (int kt = 0; kt < 8; ++kt) {
        ah[kt] = *(const short8*)&Xh[l31][kt * 16 + half * 8];
        al[kt] = *(const short8*)&Xl[l31][kt * 16 + half * 8];
    }

    short8 bh0[8], bl0[8];
    LOADB(0, bh0, bl0);
    COMPSTORE(bh0, bl0, bQ, qo, HID, 0);
    LOADB(1, bh0, bl0);
    COMPSTORE(bh0, bl0, bK, kvo, 256, 0);
    LOADB(2, bh0, bl0);
    COMPSTORE(bh0, bl0, bV, kvo, 256, 128);
}

// ---------------- fused WO+res -> LN2 -> W1+relu -> W2+res -> LN1' -> QKV' ----------------
__global__ __launch_bounds__(256, 3) void post_qkv_mfma(
    const float* __restrict__ at, const float* __restrict__ hin,
    const unsigned short* __restrict__ wnh, const unsigned short* __restrict__ wnl,
    int matbase,                      // l*6; WO=+3, W1=+4, W2=+5, next QKV=+6,+7,+8
    const float* __restrict__ bO,
    const float* __restrict__ g2, const float* __restrict__ b2g,
    const float* __restrict__ b1, const float* __restrict__ b2,
    float* __restrict__ hout,
    int doQkv,
    const float* __restrict__ g1n, const float* __restrict__ b1n,
    const float* __restrict__ bQn, const float* __restrict__ bKn, const float* __restrict__ bVn,
    float* __restrict__ qout, float* __restrict__ kvout,
    unsigned short* __restrict__ hbout,   // bf16 h, written on last layer
    int M)
{
    __shared__ unsigned short Ah[32][XS];
    __shared__ unsigned short Al[32][XS];
    __shared__ unsigned short Th[32][XS];
    __shared__ unsigned short Tl[32][XS];
    __shared__ float Hs[32][132];
    int tid = threadIdx.x;
    int lane = tid & 63, wave = tid >> 6;
    int rowBase = blockIdx.x * 32;
    int l31 = lane & 31;
    int half = lane >> 5;

    for (int i = tid; i < 32 * 32; i += 256) {
        int r = i >> 5, c4 = i & 31;
        int row = rowBase + r;
        float4 va = make_float4(0.f, 0.f, 0.f, 0.f), vh = va;
        if (row < M) {
            va = *(const float4*)&at[(size_t)row * HID + c4 * 4];
            vh = *(const float4*)&hin[(size_t)row * HID + c4 * 4];
        }
        const float* vp = (const float*)&va;
#pragma unroll
        for (int q = 0; q < 4; ++q) {
            unsigned short hi = f2bf(vp[q]);
            Ah[r][c4 * 4 + q] = hi;
            Al[r][c4 * 4 + q] = f2bf(vp[q] - bf2f(hi));
        }
        *(float4*)&Hs[r][c4 * 4] = vh;
    }
    __syncthreads();

    int colW = wave * 32 + l31;

    // GEMM1: Hs += at @ WO + bO
    {
        short8 ah[8], al[8];
#pragma unroll
        for (int kt = 0; kt < 8; ++kt) {
            ah[kt] = *(const short8*)&Ah[l31][kt * 16 + half * 8];
            al[kt] = *(const short8*)&Al[l31][kt * 16 + half * 8];
        }
        short8 bh[8], bl[8];
        {
            size_t fb = (((size_t)(matbase + 3) * 32 + (size_t)wave * 8) * 64 + lane) * 8;
            const unsigned short* Bh = wnh + fb;
            const unsigned short* Bl = wnl + fb;
#pragma unroll
            for (int kt = 0; kt < 8; ++kt) {
                bh[kt] = *(const short8*)&Bh[kt * 512];
                bl[kt] = *(const short8*)&Bl[kt * 512];
            }
            __builtin_amdgcn_sched_barrier(0);
        }
        f32x16 acc = {};
#pragma unroll
        for (int kt = 0; kt < 8; ++kt)
            acc = __builtin_amdgcn_mfma_f32_32x32x16_bf16(ah[kt], bh[kt], acc, 0, 0, 0);
#pragma unroll
        for (int kt = 0; kt < 8; ++kt)
            acc = __builtin_amdgcn_mfma_f32_32x32x16_bf16(al[kt], bh[kt], acc, 0, 0, 0);
#pragma unroll
        for (int kt = 0; kt < 8; ++kt)
            acc = __builtin_amdgcn_mfma_f32_32x32x16_bf16(ah[kt], bl[kt], acc, 0, 0, 0);
        float bv = bO[colW];
#pragma unroll
        for (int r = 0; r < 16; ++r) {
            int rowm = (r & 3) + 8 * (r >> 2) + 4 * half;
            Hs[rowm][colW] += acc[r] + bv;
        }
    }
    __syncthreads();

    // LN2 (row-parallel)
    PAR_LN(Hs, g2, b2g, Ah, Al);
    __syncthreads();

    // GEMM2: T = relu(x @ W1 + b1)
    {
        short8 ah[8], al[8];
#pragma unroll
        for (int kt = 0; kt < 8; ++kt) {
            ah[kt] = *(const short8*)&Ah[l31][kt * 16 + half * 8];
            al[kt] = *(const short8*)&Al[l31][kt * 16 + half * 8];
        }
        short8 bh[8], bl[8];
        {
            size_t fb = (((size_t)(matbase + 4) * 32 + (size_t)wave * 8) * 64 + lane) * 8;
            const unsigned short* Bh = wnh + fb;
            const unsigned short* Bl = wnl + fb;
#pragma unroll
            for (int kt = 0; kt < 8; ++kt) {
                bh[kt] = *(const short8*)&Bh[kt * 512];
                bl[kt] = *(const short8*)&Bl[kt * 512];
            }
            __builtin_amdgcn_sched_barrier(0);
        }
        f32x16 acc = {};
#pragma unroll
        for (int kt = 0; kt < 8; ++kt)
            acc = __builtin_amdgcn_mfma_f32_32x32x16_bf16(ah[kt], bh[kt], acc, 0, 0, 0);
#pragma unroll
        for (int kt = 0; kt < 8; ++kt)
            acc = __builtin_amdgcn_mfma_f32_32x32x16_bf16(al[kt], bh[kt], acc, 0, 0, 0);
#pragma unroll
        for (int kt = 0; kt < 8; ++kt)
            acc = __builtin_amdgcn_mfma_f32_32x32x16_bf16(ah[kt], bl[kt], acc, 0, 0, 0);
        float bv = b1[colW];
#pragma unroll
        for (int r = 0; r < 16; ++r) {
            int rowm = (r & 3) + 8 * (r >> 2) + 4 * half;
            float t = fmaxf(acc[r] + bv, 0.f);
            unsigned short hi = f2bf(t);
            Th[rowm][colW] = hi;
            Tl[rowm][colW] = f2bf(t - bf2f(hi));
        }
    }
    __syncthreads();

    // GEMM3: hn = Hs + T @ W2 + b2
    {
        short8 ah[8], al[8];
#pragma unroll
        for (int kt = 0; kt < 8; ++kt) {
            ah[kt] = *(const short8*)&Th[l31][kt * 16 + half * 8];
            al[kt] = *(const short8*)&Tl[l31][kt * 16 + half * 8];
        }
        short8 bh[8], bl[8];
        {
            size_t fb = (((size_t)(matbase + 5) * 32 + (size_t)wave * 8) * 64 + lane) * 8;
            const unsigned short* Bh = wnh + fb;
            const unsigned short* Bl = wnl + fb;
#pragma unroll
            for (int kt = 0; kt < 8; ++kt) {
                bh[kt] = *(const short8*)&Bh[kt * 512];
                bl[kt] = *(const short8*)&Bl[kt * 512];
            }
            __builtin_amdgcn_sched_barrier(0);
        }
        f32x16 acc = {};
#pragma unroll
        for (int kt = 0; kt < 8; ++kt)
            acc = __builtin_amdgcn_mfma_f32_32x32x16_bf16(ah[kt], bh[kt], acc, 0, 0, 0);
#pragma unroll
        for (int kt = 0; kt < 8; ++kt)
            acc = __builtin_amdgcn_mfma_f32_32x32x16_bf16(al[kt], bh[kt], acc, 0, 0, 0);
#pragma unroll
        for (int kt = 0; kt < 8; ++kt)
            acc = __builtin_amdgcn_mfma_f32_32x32x16_bf16(ah[kt], bl[kt], acc, 0, 0, 0);
        float bv = b2[colW];
#pragma unroll
        for (int r = 0; r < 16; ++r) {
            int rowm = (r & 3) + 8 * (r >> 2) + 4 * half;
            int row = rowBase + rowm;
            float hn = Hs[rowm][colW] + acc[r] + bv;
            Hs[rowm][colW] = hn;
            if (row < M) {
                if (doQkv) hout[(size_t)row * HID + colW] = hn;
                else       hbout[(size_t)row * HID + colW] = f2bf(hn);
            }
        }
    }

    if (!doQkv) return;
    __syncthreads();

    // LN1 (next layer) row-parallel
    PAR_LN(Hs, g1n, b1n, Ah, Al);
    __syncthreads();

    // QKV (next layer) — serial B loads (live set < 170-VGPR cap of (256,3))
    {
        short8 ah[8], al[8];
#pragma unroll
        for (int kt = 0; kt < 8; ++kt) {
            ah[kt] = *(const short8*)&Ah[l31][kt * 16 + half * 8];
            al[kt] = *(const short8*)&Al[l31][kt * 16 + half * 8];
        }
        short8 bh0[8], bl0[8];
        LOADB(6, bh0, bl0);
        COMPSTORE(bh0, bl0, bQn, qout, HID, 0);
        LOADB(7, bh0, bl0);
        COMPSTORE(bh0, bl0, bKn, kvout, 256, 0);
        LOADB(8, bh0, bl0);
        COMPSTORE(bh0, bl0, bVn, kvout, 256, 128);
    }
}

// ---------------- CSR build ----------------
__global__ __launch_bounds__(256) void deg_kernel(
    const int* __restrict__ dst, int* __restrict__ deg, int E)
{
    int e = blockIdx.x * 256 + threadIdx.x;
    if (e < E) atomicAdd(&deg[dst[e]], 1);
}

__global__ __launch_bounds__(256) void scan_kernel(
    const int* __restrict__ deg, int* __restrict__ rowptr,
    int* __restrict__ cursor, int N)
{
    __shared__ int sums[256];
    int tid = threadIdx.x;
    int chunk = (N + 255) / 256;
    int lo = tid * chunk;
    int hi = lo + chunk; if (hi > N) hi = N;
    int s = 0;
    for (int i = lo; i < hi && i >= 0; ++i) s += deg[i];
    sums[tid] = s;
    __syncthreads();
    for (int off = 1; off < 256; off <<= 1) {
        int v = (tid >= off) ? sums[tid - off] : 0;
        __syncthreads();
        sums[tid] += v;
        __syncthreads();
    }
    int base = (tid == 0) ? 0 : sums[tid - 1];
    for (int i = lo; i < hi; ++i) {
        rowptr[i] = base; cursor[i] = base; base += deg[i];
    }
    if (tid == 255) rowptr[N] = sums[255];
}

__global__ __launch_bounds__(256) void scatter_kernel(
    const int* __restrict__ src, const int* __restrict__ dst,
    int* __restrict__ cursor, int* __restrict__ ssrc, int E)
{
    int e = blockIdx.x * 256 + threadIdx.x;
    if (e < E) {
        int p = atomicAdd(&cursor[dst[e]], 1);
        ssrc[p] = src[e];
    }
}

// ---------------- fused segment-softmax attention (r8: 2 waves per node) ----------------
__global__ __launch_bounds__(256) void attn_fused_kernel(
    const float* __restrict__ q, const float* __restrict__ kv,
    const int* __restrict__ rowptr, const int* __restrict__ ssrc,
    float* __restrict__ at, int N)
{
    __shared__ float red[2][2][4][64];   // [nodeSlot][half][acc0,acc1,den0,den1][lane]
    int tid = threadIdx.x;
    int wv = tid >> 6;
    int lane = tid & 63;
    int slot = wv >> 1;
    int hf = wv & 1;
    int node = blockIdx.x * 2 + slot;

    float acc0 = 0.f, acc1 = 0.f, den0 = 0.f, den1 = 0.f;
    if (node < N) {
        int beg = rowptr[node], end = rowptr[node + 1];
        int lenA = (end - beg + 1) >> 1;
        int b = hf ? (beg + lenA) : beg;
        int e = hf ? end : (beg + lenA);
        float q0 = q[(size_t)node * HID + lane];
        float q1 = q[(size_t)node * HID + 64 + lane];
        int i = b;
        for (; i + 2 <= e; i += 2) {
            int s0 = ssrc[i], s1 = ssrc[i + 1];
            const float* kv0 = kv + (size_t)s0 * 256;
            const float* kv1 = kv + (size_t)s1 * 256;
            float k00 = kv0[lane],       k01 = kv0[64 + lane];
            float v00 = kv0[128 + lane], v01 = kv0[192 + lane];
            float k10 = kv1[lane],       k11 = kv1[64 + lane];
            float v10 = kv1[128 + lane], v11 = kv1[192 + lane];
            float p00 = q0 * k00, p01 = q1 * k01;
            float p10 = q0 * k10, p11 = q1 * k11;
#pragma unroll
            for (int off = 1; off < 16; off <<= 1) {
                p00 += __shfl_xor(p00, off, 64);
                p01 += __shfl_xor(p01, off, 64);
                p10 += __shfl_xor(p10, off, 64);
                p11 += __shfl_xor(p11, off, 64);
            }
            float w00 = __expf(p00 * 0.25f), w01 = __expf(p01 * 0.25f);
            float w10 = __expf(p10 * 0.25f), w11 = __expf(p11 * 0.25f);
            den0 += w00 + w10; den1 += w01 + w11;
            acc0 = fmaf(w10, v10, fmaf(w00, v00, acc0));
            acc1 = fmaf(w11, v11, fmaf(w01, v01, acc1));
        }
        if (i < e) {
            int s = ssrc[i];
            const float* kv0 = kv + (size_t)s * 256;
            float k0 = kv0[lane], k1 = kv0[64 + lane];
            float p0 = q0 * k0, p1 = q1 * k1;
#pragma unroll
            for (int off = 1; off < 16; off <<= 1) {
                p0 += __shfl_xor(p0, off, 64);
                p1 += __shfl_xor(p1, off, 64);
            }
            float w0 = __expf(p0 * 0.25f), w1 = __expf(p1 * 0.25f);
            den0 += w0; den1 += w1;
            acc0 = fmaf(w0, kv0[128 + lane], acc0);
            acc1 = fmaf(w1, kv0[192 + lane], acc1);
        }
    }
    red[slot][hf][0][lane] = acc0;
    red[slot][hf][1][lane] = acc1;
    red[slot][hf][2][lane] = den0;
    red[slot][hf][3][lane] = den1;
    __syncthreads();

    if (hf == 0 && node < N) {
        float a0 = red[slot][0][0][lane] + red[slot][1][0][lane];
        float a1 = red[slot][0][1][lane] + red[slot][1][1][lane];
        float d0 = red[slot][0][2][lane] + red[slot][1][2][lane];
        float d1 = red[slot][0][3][lane] + red[slot][1][3][lane];
        at[(size_t)node * HID + lane]      = (d0 > 0.f) ? a0 / d0 : 0.f;
        at[(size_t)node * HID + 64 + lane] = (d1 > 0.f) ? a1 / d1 : 0.f;
    }
}

// ---------------- prep: fragment-major packed bf16 MLP hidden weights ----------------
__global__ __launch_bounds__(256) void prep_wp_kernel(
    const float* __restrict__ Wh, unsigned short* __restrict__ wp)
{
    int idx = blockIdx.x * 256 + threadIdx.x;
    if (idx >= 3 * 9 * 18 * 64) return;
    int lane = idx & 63;
    int r = idx >> 6;
    int kt = r % 18; r /= 18;
    int ct = r % 9;
    int layer = r / 9;
    int n = ct * 32 + (lane & 31);
    int kbase = kt * 16 + (lane >> 5) * 8;
    ushort8 val;
#pragma unroll
    for (int j = 0; j < 8; ++j) {
        int k = kbase + j;
        float v = (n < MLP_IN && k < MLP_IN)
            ? Wh[(size_t)layer * MLP_IN * MLP_IN + (size_t)k * MLP_IN + n] : 0.f;
        val[j] = f2bf(v);
    }
    *(ushort8*)&wp[(size_t)idx * 8] = val;
}

// ---------------- fused edge classifier MLP (r12: best measured, 278-286us) ----------------
// 32 edges / 4 waves per block; waves share the 32-row slab (afr over all 18 kt),
// cts split ct = wave, wave+4. LDS 18,944 B; (256,4) -> 60 VGPR, no spill,
// ~13 waves/CU. NO sched_barrier fence in the inner loop (r13 proved it spills
// under the 128-reg cap: WRITE_SIZE 1.5MB -> 844MB, dur 605us).
__global__ __launch_bounds__(256, 4) void edge_mlp_mfma(
    const unsigned short* __restrict__ hb, const float* __restrict__ ce,
    const float* __restrict__ pe, const float* __restrict__ num,
    const int* __restrict__ src, const int* __restrict__ dst,
    const int* __restrict__ pc, const int* __restrict__ rc,
    const int* __restrict__ pf,
    const unsigned short* __restrict__ wp, const float* __restrict__ bh,
    const float* __restrict__ Wo, const float* __restrict__ bo,
    float* __restrict__ out, int E)
{
    __shared__ unsigned short y[32 * LDW];   // 18,944 B
    int tid = threadIdx.x;
    int e0 = blockIdx.x * 32;
    int wave = tid >> 6;
    int lane = tid & 63;
    int l31 = lane & 31;
    int half = lane >> 5;

    // stage inputs into y (cols 285-287 zeroed via c==35 tail)
    for (int i = tid; i < 32 * 36; i += 256) {
        int t = i / 36;
        int c = i - t * 36;
        int e = e0 + t;
        if (e >= E) e = E - 1;
        ushort8 val;
        if (c < 16) {
            val = *(const ushort8*)&hb[(size_t)src[e] * HID + c * 8];
        } else if (c < 32) {
            val = *(const ushort8*)&hb[(size_t)dst[e] * HID + (c - 16) * 8];
        } else if (c == 32) {
            const float* p = &ce[pc[e] * 8];
#pragma unroll
            for (int j = 0; j < 8; ++j) val[j] = f2bf(p[j]);
        } else if (c == 33) {
            const float* p = &ce[rc[e] * 8];
#pragma unroll
            for (int j = 0; j < 8; ++j) val[j] = f2bf(p[j]);
        } else if (c == 34) {
            const float* p = &pe[pf[e] * 8];
#pragma unroll
            for (int j = 0; j < 8; ++j) val[j] = f2bf(p[j]);
        } else {
            const float* p = &num[(size_t)e * 5];
#pragma unroll
            for (int j = 0; j < 5; ++j) val[j] = f2bf(p[j]);
            val[5] = 0; val[6] = 0; val[7] = 0;
        }
        *(ushort8*)&y[t * LDW + c * 8] = val;
    }
    __syncthreads();

    for (int layer = 0; layer < 3; ++layer) {
        const float* __restrict__ bias = bh + layer * MLP_IN;

        short8 afr[18];
#pragma unroll
        for (int kt = 0; kt < 18; ++kt)
            afr[kt] = *(const short8*)&y[l31 * LDW + kt * 16 + half * 8];
        __syncthreads();   // all reads done before anyone overwrites y

        for (int ct = wave; ct < 9; ct += 4) {
            const unsigned short* __restrict__ Bp =
                wp + (size_t)layer * 82944 + (size_t)ct * 9216 + (size_t)lane * 8;
            short8 bfr[18];
#pragma unroll
            for (int kt = 0; kt < 18; ++kt)
                bfr[kt] = *(const short8*)&Bp[kt * 512];
            f32x16 acc = {};
#pragma unroll
            for (int kt = 0; kt < 18; ++kt)
                acc = __builtin_amdgcn_mfma_f32_32x32x16_bf16(afr[kt], bfr[kt], acc, 0, 0, 0);
            int col = ct * 32 + l31;
            if (col < MLP_IN) {
                float bv = bias[col];
#pragma unroll
                for (int r = 0; r < 16; ++r) {
                    int rowm = (r & 3) + 8 * (r >> 2) + 4 * half;
                    float t = fmaxf(acc[r] + bv, 0.f);
                    y[rowm * LDW + col] = f2bf(t);
                }
            }
        }
        __syncthreads();   // writes done before next layer's reads
    }

    // final 285x2 projection: 4 threads per edge (oc x K-half), shfl-combine
    {
        int t = tid >> 2;            // 0..63, only t<32 valid
        int oc = tid & 1;
        int kk = (tid >> 1) & 1;
        int e = e0 + t;
        if (t < 32) {
            const unsigned short* yr = &y[t * LDW];
            float p0 = 0.f, p1 = 0.f, p2 = 0.f, p3 = 0.f;
            int kc_lo = kk ? 18 : 0;
            int kc_hi = kk ? 35 : 18;
            for (int kc = kc_lo; kc < kc_hi; ++kc) {
                ushort8 yv = *(const ushort8*)&yr[kc * 8];
                int kb = kc * 8;
                p0 = fmaf(bf2f(yv[0]), Wo[(kb + 0) * 2 + oc], p0);
                p1 = fmaf(bf2f(yv[1]), Wo[(kb + 1) * 2 + oc], p1);
                p2 = fmaf(bf2f(yv[2]), Wo[(kb + 2) * 2 + oc], p2);
                p3 = fmaf(bf2f(yv[3]), Wo[(kb + 3) * 2 + oc], p3);
                p0 = fmaf(bf2f(yv[4]), Wo[(kb + 4) * 2 + oc], p0);
                p1 = fmaf(bf2f(yv[5]), Wo[(kb + 5) * 2 + oc], p1);
                p2 = fmaf(bf2f(yv[6]), Wo[(kb + 6) * 2 + oc], p2);
                p3 = fmaf(bf2f(yv[7]), Wo[(kb + 7) * 2 + oc], p3);
            }
            float acc = (p0 + p1) + (p2 + p3);
            if (kk) {
                for (int k = 280; k < MLP_IN; ++k)
                    acc = fmaf(bf2f(yr[k]), Wo[k * 2 + oc], acc);
            }
            acc += __shfl_xor(acc, 2, 64);
            if (kk == 0 && e < E)
                out[(size_t)e * 2 + oc] = acc + bo[oc];
        }
    }
}

extern "C" void kernel_launch(void* const* d_in, const int* in_sizes, int n_in,
                              void* d_out, int out_size, void* d_ws, size_t ws_size,
                              hipStream_t stream)
{
    const float* node_feats = (const float*)d_in[0];
    const float* numericals = (const float*)d_in[1];
    const float* W_emb = (const float*)d_in[2];
    const float* b_emb = (const float*)d_in[3];
    const float* WQ = (const float*)d_in[4];
    const float* bQ = (const float*)d_in[5];
    const float* WK = (const float*)d_in[6];
    const float* bK = (const float*)d_in[7];
    const float* WV = (const float*)d_in[8];
    const float* bV = (const float*)d_in[9];
    const float* WO = (const float*)d_in[10];
    const float* bO = (const float*)d_in[11];
    const float* ln1_g = (const float*)d_in[12];
    const float* ln1_b = (const float*)d_in[13];
    const float* ln2_g = (const float*)d_in[14];
    const float* ln2_b = (const float*)d_in[15];
    const float* W1 = (const float*)d_in[16];
    const float* b1 = (const float*)d_in[17];
    const float* W2 = (const float*)d_in[18];
    const float* b2 = (const float*)d_in[19];
    const float* curr_emb = (const float*)d_in[20];
    const float* pay_emb = (const float*)d_in[21];
    const float* mlp_Wh = (const float*)d_in[22];
    const float* mlp_bh = (const float*)d_in[23];
    const float* mlp_Wo = (const float*)d_in[24];
    const float* mlp_bo = (const float*)d_in[25];
    const int* src = (const int*)d_in[26];
    const int* dst = (const int*)d_in[27];
    const int* pc = (const int*)d_in[28];
    const int* rc = (const int*)d_in[29];
    const int* pf = (const int*)d_in[30];

    const int N = in_sizes[0] / 2;
    const int E = in_sizes[26];

    float* ws = (float*)d_ws;
    float* h    = ws;
    float* qb0  = h    + (size_t)N * HID;
    float* kvb0 = qb0  + (size_t)N * HID;
    float* qb1  = kvb0 + (size_t)N * HID * 2;
    float* kvb1 = qb1  + (size_t)N * HID;
    float* at   = kvb1 + (size_t)N * HID * 2;
    unsigned short* hb = (unsigned short*)(at + (size_t)N * HID);
    unsigned short* wpk = hb + (size_t)N * HID;
    unsigned short* wnh = wpk + (size_t)3 * 9 * 18 * 64 * 8;
    unsigned short* wnl = wnh + (size_t)42 * 32 * 64 * 8;
    int* rowptr = (int*)(wnl + (size_t)42 * 32 * 64 * 8);
    int* deg    = rowptr + (N + 1);
    int* cursor = deg + N;
    int* ssrc   = cursor + N;

    prep_wp_kernel<<<(3 * 9 * 18 * 64 + 255) / 256, 256, 0, stream>>>(mlp_Wh, wpk);
    prep_nodew_kernel<<<(42 * 32 * 64 + 255) / 256, 256, 0, stream>>>(
        WQ, WK, WV, WO, W1, W2, wnh, wnl);

    embed_kernel<<<(N * HID + 255) / 256, 256, 0, stream>>>(node_feats, W_emb, b_emb, h, N);

    hipMemsetAsync(deg, 0, (size_t)N * sizeof(int), stream);
    deg_kernel<<<(E + 255) / 256, 256, 0, stream>>>(dst, deg, E);
    scan_kernel<<<1, 256, 0, stream>>>(deg, rowptr, cursor, N);
    scatter_kernel<<<(E + 255) / 256, 256, 0, stream>>>(src, dst, cursor, ssrc, E);

    int nodeBlocks = (N + 31) / 32;

    // layer 0 QKV
    ln_qkv_mfma<<<nodeBlocks, 256, 0, stream>>>(
        h, ln1_g, ln1_b, wnh, wnl, 0,
        bQ, bK, bV, qb0, kvb0, N);

    float* qbuf[2]  = { qb0, qb1 };
    float* kvbuf[2] = { kvb0, kvb1 };

    for (int l = 0; l < NLAYERS; ++l) {
        int cur = l & 1, nxt = cur ^ 1;
        int doQkv = (l < NLAYERS - 1) ? 1 : 0;
        int ln = (l + 1 < NLAYERS) ? (l + 1) : 0;

        attn_fused_kernel<<<(N + 1) / 2, 256, 0, stream>>>(
            qbuf[cur], kvbuf[cur], rowptr, ssrc, at, N);

        post_qkv_mfma<<<nodeBlocks, 256, 0, stream>>>(
            at, h, wnh, wnl, l * 6,
            bO + l * HID,
            ln2_g + l * HID, ln2_b + l * HID,
            b1 + l * HID, b2 + l * HID,
            h, doQkv,
            ln1_g + ln * HID, ln1_b + ln * HID,
            bQ + ln * HID, bK + ln * HID, bV + ln * HID,
            qbuf[nxt], kvbuf[nxt],
            hb, N);
    }

    edge_mlp_mfma<<<(E + 31) / 32, 256, 0, stream>>>(
        hb, curr_emb, pay_emb, numericals, src, dst, pc, rc, pf,
        wpk, mlp_bh, mlp_Wo, mlp_bo, (float*)d_out, E);
}